// Round 1
// 1777.737 us; speedup vs baseline: 3.3601x; 3.3601x over previous
//
#include <hip/hip_runtime.h>

// Softsplat forward (summation splatting), B=4, C=64, H=512, W=512, fp32.
//
// v2: tiled LDS accumulation. The previous per-pixel scatter kernel showed
// 4.9 GB HBM WRITE_SIZE (19x amplification) and VALUBusy 0.4% -> bound by
// scattered global atomics, not bandwidth. Flow ~ N(0,1) => splat targets are
// within a few pixels of the source, so each 32x32 source tile accumulates
// into an LDS tile with a +-6 halo (LDS atomics), then flushes once to global
// with coalesced atomics. Out-of-halo taps (astronomically rare for this
// input, but legal) fall back to direct global atomicAdd for correctness.

#define B_ 4
#define C_ 64
#define H_ 512
#define W_ 512
#define HW_ (H_ * W_)

#define TH 32                      // tile rows (source pixels)
#define TW 32                      // tile cols
#define HALO 6                     // halo on each side
#define LH (TH + 2 * HALO)         // 44
#define LW (TW + 2 * HALO)         // 44
#define TILE_CELLS (LH * LW)       // 1936
#define CCHUNK 4                   // channels accumulated per LDS pass
#define NTHREADS 256
#define PXPT ((TH * TW) / NTHREADS)        // 4 pixels per thread
#define LDS_FLOATS (CCHUNK * TILE_CELLS)   // 7744 floats = 30976 B

__global__ __launch_bounds__(NTHREADS) void softsplat_fwd(
    const float* __restrict__ image,   // [B, C, H, W]
    const float* __restrict__ flow,    // [B, 2, H, W]
    float* __restrict__ out)           // [B, C, H, W], pre-zeroed
{
    __shared__ float lds[LDS_FLOATS];

    const int tid = threadIdx.x;
    const int tx = blockIdx.x;         // tile col index
    const int ty = blockIdx.y;         // tile row index
    const int b  = blockIdx.z;
    const int tileX0 = tx * TW - HALO; // global x of lds cell (.,0)
    const int tileY0 = ty * TH - HALO;

    // Load flow once; keep destination coords in registers across all chunks.
    float fx[PXPT], fy[PXPT];
    int   px[PXPT], py[PXPT];
    #pragma unroll
    for (int k = 0; k < PXPT; ++k) {
        int pi = k * NTHREADS + tid;
        int ly = pi >> 5;              // TW = 32
        int lx = pi & (TW - 1);
        int y = ty * TH + ly;
        int x = tx * TW + lx;
        px[k] = x; py[k] = y;
        size_t fo = (size_t)b * 2 * HW_ + (size_t)y * W_ + x;
        fx[k] = flow[fo] + (float)x;           // coalesced
        fy[k] = flow[fo + HW_] + (float)y;
    }

    for (int c0 = 0; c0 < C_; c0 += CCHUNK) {
        // 1) zero the LDS accumulation tile
        for (int i = tid; i < LDS_FLOATS; i += NTHREADS) lds[i] = 0.0f;
        __syncthreads();

        // 2) accumulate 4 bilinear taps for CCHUNK channels into LDS
        #pragma unroll
        for (int k = 0; k < PXPT; ++k) {
            float x0f = floorf(fx[k]);
            float y0f = floorf(fy[k]);
            int x0 = (int)x0f, y0 = (int)y0f;
            float wx1 = fx[k] - x0f, wx0 = 1.0f - wx1;
            float wy1 = fy[k] - y0f, wy0 = 1.0f - wy1;

            int   gxs[2] = { x0, x0 + 1 };
            int   gys[2] = { y0, y0 + 1 };
            float wxs[2] = { wx0, wx1 };
            float wys[2] = { wy0, wy1 };

            const float* imgp = image + ((size_t)(b * C_ + c0)) * HW_
                              + (size_t)py[k] * W_ + px[k];

            #pragma unroll
            for (int cc = 0; cc < CCHUNK; ++cc) {
                float val = imgp[(size_t)cc * HW_];   // coalesced across lanes
                float* ldsc = lds + cc * TILE_CELLS;
                float* outc = out + ((size_t)(b * C_ + c0 + cc)) * HW_;
                #pragma unroll
                for (int t = 0; t < 4; ++t) {
                    int gx = gxs[t & 1], gy = gys[t >> 1];
                    float w = wxs[t & 1] * wys[t >> 1];
                    bool in_img = ((unsigned)gx < W_) & ((unsigned)gy < H_);
                    int lxi = gx - tileX0;
                    int lyi = gy - tileY0;
                    bool in_lds = ((unsigned)lxi < LW) & ((unsigned)lyi < LH);
                    if (in_img) {
                        if (in_lds) {
                            atomicAdd(ldsc + lyi * LW + lxi, val * w);  // ds_add
                        } else {
                            // out-of-halo fallback (rare; correctness only)
                            atomicAdd(outc + (size_t)gy * W_ + gx, val * w);
                        }
                    }
                }
            }
        }
        __syncthreads();

        // 3) flush LDS tile to global with coalesced atomics, skipping zeros
        for (int e = tid; e < LDS_FLOATS; e += NTHREADS) {
            float v = lds[e];
            if (v != 0.0f) {
                int cc  = e / TILE_CELLS;
                int r   = e - cc * TILE_CELLS;
                int lly = r / LW;
                int llx = r - lly * LW;
                int gy = tileY0 + lly;
                int gx = tileX0 + llx;
                if (((unsigned)gx < W_) & ((unsigned)gy < H_)) {
                    atomicAdd(out + ((size_t)(b * C_ + c0 + cc)) * HW_
                                  + (size_t)gy * W_ + gx, v);
                }
            }
        }
        __syncthreads();   // protect LDS from next iteration's zeroing
    }
}

extern "C" void kernel_launch(void* const* d_in, const int* in_sizes, int n_in,
                              void* d_out, int out_size, void* d_ws, size_t ws_size,
                              hipStream_t stream) {
    const float* image = (const float*)d_in[0];
    const float* flow  = (const float*)d_in[1];
    float* out = (float*)d_out;

    // d_out is poisoned before every call — zero it on-stream.
    hipMemsetAsync(out, 0, (size_t)out_size * sizeof(float), stream);

    dim3 grid(W_ / TW, H_ / TH, B_);   // 16 x 16 x 4 = 1024 workgroups
    softsplat_fwd<<<grid, NTHREADS, 0, stream>>>(image, flow, out);
}

// Round 2
// 996.031 us; speedup vs baseline: 5.9971x; 1.7848x over previous
//
#include <hip/hip_runtime.h>

// Softsplat forward (summation splatting), B=4, C=64, H=512, W=512, fp32.
//
// v3: atomic-free GATHER formulation. v2's counters (VALUBusy 7%, HBM 5%,
// 270 cyc/instr stall) showed the 268M LDS atomics + 105M global atomics were
// the wall. Invert the scatter: a source with fx,fy in [-6,6) only reaches
// outputs within +-6, so a 16x16 output tile gathers exclusively from its
// 28x28 source window (<=3136 contributions, hard bound -> exact CSR list in
// LDS, built once, reused across 64 channels). Output written with plain
// coalesced stores (no memset, no RMW). Sources with |flow|>=6 ("wild",
// ~never for N(0,1) but required for correctness) are scatter-added by a
// second kernel AFTER the gather stores.

#define B_ 4
#define C_ 64
#define H_ 512
#define W_ 512
#define HW_ (H_ * W_)

#define TS 16                 // output tile side
#define R_ 6                  // gather radius; |flow| >= R_ -> wild path
#define WS (TS + 2 * R_)      // 28: source window side
#define NSRC (WS * WS)        // 784
#define MAXE (NSRC * 4)       // 3136: hard bound on per-tile contributions
#define CCH 8                 // channels staged per pass
#define IMG_STRIDE 788        // 788 % 32 = 20 -> 8 channel rows hit 8 banks
#define NTH 256

__global__ __launch_bounds__(NTH) void softsplat_gather(
    const float* __restrict__ image,   // [B, C, H, W]
    const float* __restrict__ flow,    // [B, 2, H, W]
    float* __restrict__ out)           // [B, C, H, W] (written fully, no prezero)
{
    __shared__ float s_ax[NSRC];            // dest x, tile-relative (1e9 = skip)
    __shared__ float s_ay[NSRC];
    __shared__ unsigned short s_idx[MAXE];  // CSR: source index per entry
    __shared__ float s_w[MAXE];             // CSR: weight per entry
    __shared__ float s_img[CCH * IMG_STRIDE];
    __shared__ unsigned s_cnt[TS * TS];     // counts, then fill cursor
    __shared__ unsigned s_off[TS * TS];     // inclusive prefix sum

    const int tid = threadIdx.x;
    const int T0x = blockIdx.x * TS;
    const int T0y = blockIdx.y * TS;
    const int b   = blockIdx.z;

    s_cnt[tid] = 0u;
    __syncthreads();

    // ---- L1: scan window, store tile-relative dest coords, count taps ----
    const float* flb = flow + (size_t)b * 2 * HW_;
    for (int s = tid; s < NSRC; s += NTH) {
        int row = s / WS, col = s - row * WS;
        int syg = T0y - R_ + row, sxg = T0x - R_ + col;
        float ax = 1.0e9f, ay = 1.0e9f;
        if (((unsigned)syg < H_) & ((unsigned)sxg < W_)) {
            size_t fo = (size_t)syg * W_ + sxg;
            float fxr = flb[fo];
            float fyr = flb[fo + HW_];
            // non-wild test: floor(f) in [-R, R-1] guarantees taps within +-R
            if (fxr >= -(float)R_ && fxr < (float)R_ &&
                fyr >= -(float)R_ && fyr < (float)R_) {
                ax = fxr + (float)(sxg - T0x);   // exact in fp32
                ay = fyr + (float)(syg - T0y);
            }
        }
        s_ax[s] = ax;
        s_ay[s] = ay;
        if (ax < 1.0e8f) {
            int x0 = (int)floorf(ax), y0 = (int)floorf(ay);
            #pragma unroll
            for (int t = 0; t < 4; ++t) {
                int tx = x0 + (t & 1), ty = y0 + (t >> 1);
                if (((unsigned)tx < TS) & ((unsigned)ty < TS))
                    atomicAdd(&s_cnt[ty * TS + tx], 1u);
            }
        }
    }
    __syncthreads();

    // ---- L2: inclusive scan (Hillis-Steele, 256 elems) ----
    unsigned v0 = s_cnt[tid];
    s_off[tid] = v0;
    __syncthreads();
    for (int d = 1; d < NTH; d <<= 1) {
        unsigned u = 0;
        if (tid >= d) u = s_off[tid - d];
        __syncthreads();
        s_off[tid] += u;
        __syncthreads();
    }
    const unsigned estart = (tid > 0) ? s_off[tid - 1] : 0u;
    const unsigned eend   = s_off[tid];
    s_cnt[tid] = estart;            // becomes fill cursor
    __syncthreads();

    // ---- L3: fill CSR entries ----
    for (int s = tid; s < NSRC; s += NTH) {
        float ax = s_ax[s];
        if (ax < 1.0e8f) {
            float ay = s_ay[s];
            float x0f = floorf(ax), y0f = floorf(ay);
            int x0 = (int)x0f, y0 = (int)y0f;
            float wx1 = ax - x0f, wx0 = 1.0f - wx1;
            float wy1 = ay - y0f, wy0 = 1.0f - wy1;
            #pragma unroll
            for (int t = 0; t < 4; ++t) {
                int tx = x0 + (t & 1), ty = y0 + (t >> 1);
                if (((unsigned)tx < TS) & ((unsigned)ty < TS)) {
                    float w = ((t & 1) ? wx1 : wx0) * ((t >> 1) ? wy1 : wy0);
                    unsigned slot = atomicAdd(&s_cnt[ty * TS + tx], 1u);
                    s_idx[slot] = (unsigned short)s;
                    s_w[slot]   = w;
                }
            }
        }
    }
    __syncthreads();

    // ---- G: per 8-channel chunk: stage window, gather, store ----
    const int oy = tid >> 4, ox = tid & (TS - 1);
    const int gy = T0y + oy, gx = T0x + ox;
    for (int c0 = 0; c0 < C_; c0 += CCH) {
        for (int i = tid; i < CCH * NSRC; i += NTH) {
            int c = i / NSRC, s = i - c * NSRC;
            int row = s / WS, col = s - row * WS;
            int syg = T0y - R_ + row, sxg = T0x - R_ + col;
            float vimg = 0.0f;
            if (((unsigned)syg < H_) & ((unsigned)sxg < W_))
                vimg = image[((size_t)(b * C_ + c0 + c)) * HW_
                             + (size_t)syg * W_ + sxg];
            s_img[c * IMG_STRIDE + s] = vimg;
        }
        __syncthreads();

        float acc[CCH];
        #pragma unroll
        for (int c = 0; c < CCH; ++c) acc[c] = 0.0f;
        for (unsigned e = estart; e < eend; ++e) {
            int   si = s_idx[e];
            float w  = s_w[e];
            #pragma unroll
            for (int c = 0; c < CCH; ++c)
                acc[c] = fmaf(s_img[c * IMG_STRIDE + si], w, acc[c]);
        }
        #pragma unroll
        for (int c = 0; c < CCH; ++c)
            out[((size_t)(b * C_ + c0 + c)) * HW_ + (size_t)gy * W_ + gx] = acc[c];
        __syncthreads();   // s_img reused next chunk
    }
}

// Wild sources (|flow| >= R_): exact scatter with global atomics, launched
// AFTER the gather (gather writes with '='). For N(0,1) flow this kernel is
// a flow read + early exit.
__global__ __launch_bounds__(256) void softsplat_wild(
    const float* __restrict__ image,
    const float* __restrict__ flow,
    float* __restrict__ out)
{
    int p  = blockIdx.x * 256 + threadIdx.x;
    int b  = p >> 18;
    int yx = p & (HW_ - 1);
    int y  = yx >> 9;
    int x  = yx & (W_ - 1);

    size_t fo = (size_t)b * 2 * HW_ + yx;
    float fxr = flow[fo];
    float fyr = flow[fo + HW_];
    bool tame = (fxr >= -(float)R_) && (fxr < (float)R_) &&
                (fyr >= -(float)R_) && (fyr < (float)R_);
    if (tame) return;

    float fx = fxr + (float)x;
    float fy = fyr + (float)y;
    float x0f = floorf(fx), y0f = floorf(fy);
    int x0 = (int)x0f, y0 = (int)y0f;
    float wx1 = fx - x0f, wx0 = 1.0f - wx1;
    float wy1 = fy - y0f, wy0 = 1.0f - wy1;

    int   toff[4];
    float tw[4];
    int   nt = 0;
    int x1 = x0 + 1, y1 = y0 + 1;
    if (((unsigned)y0 < H_) & ((unsigned)x0 < W_)) { toff[nt] = y0 * W_ + x0; tw[nt] = wx0 * wy0; nt++; }
    if (((unsigned)y0 < H_) & ((unsigned)x1 < W_)) { toff[nt] = y0 * W_ + x1; tw[nt] = wx1 * wy0; nt++; }
    if (((unsigned)y1 < H_) & ((unsigned)x0 < W_)) { toff[nt] = y1 * W_ + x0; tw[nt] = wx0 * wy1; nt++; }
    if (((unsigned)y1 < H_) & ((unsigned)x1 < W_)) { toff[nt] = y1 * W_ + x1; tw[nt] = wx1 * wy1; nt++; }

    const float* img_b = image + (size_t)b * C_ * HW_ + yx;
    float*       out_b = out   + (size_t)b * C_ * HW_;
    for (int c = 0; c < C_; ++c) {
        float val = img_b[(size_t)c * HW_];
        float* oc = out_b + (size_t)c * HW_;
        #pragma unroll 4
        for (int t = 0; t < 4; ++t)
            if (t < nt) atomicAdd(oc + toff[t], val * tw[t]);
    }
}

extern "C" void kernel_launch(void* const* d_in, const int* in_sizes, int n_in,
                              void* d_out, int out_size, void* d_ws, size_t ws_size,
                              hipStream_t stream) {
    const float* image = (const float*)d_in[0];
    const float* flow  = (const float*)d_in[1];
    float* out = (float*)d_out;

    // No memset: gather writes every output element exactly once.
    dim3 grid(W_ / TS, H_ / TS, B_);   // 32 x 32 x 4
    softsplat_gather<<<grid, NTH, 0, stream>>>(image, flow, out);

    int pixels = B_ * HW_;
    softsplat_wild<<<pixels / 256, 256, 0, stream>>>(image, flow, out);
}

// Round 3
// 654.879 us; speedup vs baseline: 9.1212x; 1.5209x over previous
//
#include <hip/hip_runtime.h>

// Softsplat forward (summation splatting), B=4, C=64, H=512, W=512, fp32.
//
// v4: same gather formulation as v3 (exact CSR per 16x16 output tile, radius-6
// window, wild |flow|>=6 sources via follow-up scatter kernel), but the two
// measured costs of v3 are restructured away:
//  - LDS layout is channel-interleaved s_img[px][8]: gather reads 8 channels
//    with 2x ds_read_b128 + 1x packed-u32 entry read (was 10 scalar reads).
//    Entry = (w_bits & ~1023) | si  -> weight keeps 13 mantissa bits (err 2^-13).
//  - Staging uses __builtin_amdgcn_global_load_lds: the [px][8] layout is
//    linear in lane id (lane = px*8+ch), so LDS dest is wave-uniform base +
//    lane*4; the per-lane GLOBAL address carries the interleave. No ds_write,
//    no divisions (row loop, pointer increments, OOB by clamp: clamped cells
//    are garbage but never referenced by any CSR entry).
//  - XCD-aware bijective block swizzle (4096 tiles % 8 == 0).

#define B_ 4
#define C_ 64
#define H_ 512
#define W_ 512
#define HW_ (H_ * W_)

#define TS 16                  // output tile side
#define R_ 6                   // gather radius; |flow| >= R_ -> wild path
#define WSY 28                 // window rows
#define WSX 32                 // window cols padded 28 -> 32 (cols 28..31 unused)
#define NSRCP (WSY * WSX)      // 896 padded cells ( < 1024 -> si fits 10 bits)
#define MAXE (28 * 28 * 4)     // 3136 hard bound on entries
#define CCH 8                  // channels per pass
#define NTH 256

typedef __attribute__((address_space(1))) void GAS;
typedef __attribute__((address_space(3))) void LAS;

__global__ __launch_bounds__(NTH) void softsplat_gather(
    const float* __restrict__ image,   // [B, C, H, W]
    const float* __restrict__ flow,    // [B, 2, H, W]
    float* __restrict__ out)           // [B, C, H, W] (fully written, no prezero)
{
    __shared__ __align__(16) float4 s_img4[NSRCP * 2];  // [px][8ch] = 28672 B
    __shared__ unsigned s_ent[MAXE];                    // packed {w22|si10}
    __shared__ unsigned s_cnt[NTH];
    __shared__ unsigned s_off[NTH];

    const int tid = threadIdx.x;

    // XCD-aware bijective swizzle: 4096 tiles, 8 XCDs, 512 per XCD.
    int bid = blockIdx.x;
    int swz = (bid & 7) * 512 + (bid >> 3);
    const int b   = swz >> 10;
    const int rem = swz & 1023;
    const int T0y = (rem >> 5) * TS;
    const int T0x = (rem & 31) * TS;

    // ---- build phase scratch overlaid on s_img4 (dead before staging) ----
    float* s_ax = (float*)s_img4;          // [NSRCP]
    float* s_ay = (float*)s_img4 + NSRCP;  // [NSRCP]

    s_cnt[tid] = 0u;
    __syncthreads();

    // L1: scan window, tile-relative dest coords, count taps per output pixel
    const float* flb = flow + (size_t)b * 2 * HW_;
    for (int s = tid; s < NSRCP; s += NTH) {
        int row = s >> 5, col = s & 31;
        int syg = T0y - R_ + row, sxg = T0x - R_ + col;
        float ax = 1.0e9f, ay = 1.0e9f;
        if ((col < 28) & ((unsigned)syg < H_) & ((unsigned)sxg < W_)) {
            size_t fo = (size_t)syg * W_ + sxg;
            float fxr = flb[fo];
            float fyr = flb[fo + HW_];
            if (fxr >= -(float)R_ && fxr < (float)R_ &&
                fyr >= -(float)R_ && fyr < (float)R_) {
                ax = fxr + (float)(sxg - T0x);   // exact in fp32
                ay = fyr + (float)(syg - T0y);
            }
        }
        s_ax[s] = ax;
        s_ay[s] = ay;
        if (ax < 1.0e8f) {
            int x0 = (int)floorf(ax), y0 = (int)floorf(ay);
            #pragma unroll
            for (int t = 0; t < 4; ++t) {
                int tx = x0 + (t & 1), ty = y0 + (t >> 1);
                if (((unsigned)tx < TS) & ((unsigned)ty < TS))
                    atomicAdd(&s_cnt[ty * TS + tx], 1u);
            }
        }
    }
    __syncthreads();

    // L2: inclusive scan (Hillis-Steele over 256) -> per-pixel entry ranges
    unsigned v0 = s_cnt[tid];
    s_off[tid] = v0;
    __syncthreads();
    for (int d = 1; d < NTH; d <<= 1) {
        unsigned u = 0;
        if (tid >= d) u = s_off[tid - d];
        __syncthreads();
        s_off[tid] += u;
        __syncthreads();
    }
    const unsigned estart = (tid > 0) ? s_off[tid - 1] : 0u;
    const unsigned eend   = s_off[tid];
    s_cnt[tid] = estart;            // becomes fill cursor
    __syncthreads();

    // L3: fill packed CSR entries
    for (int s = tid; s < NSRCP; s += NTH) {
        float ax = s_ax[s];
        if (ax < 1.0e8f) {
            float ay = s_ay[s];
            float x0f = floorf(ax), y0f = floorf(ay);
            int x0 = (int)x0f, y0 = (int)y0f;
            float wx1 = ax - x0f, wx0 = 1.0f - wx1;
            float wy1 = ay - y0f, wy0 = 1.0f - wy1;
            #pragma unroll
            for (int t = 0; t < 4; ++t) {
                int tx = x0 + (t & 1), ty = y0 + (t >> 1);
                if (((unsigned)tx < TS) & ((unsigned)ty < TS)) {
                    float w = ((t & 1) ? wx1 : wx0) * ((t >> 1) ? wy1 : wy0);
                    unsigned slot = atomicAdd(&s_cnt[ty * TS + tx], 1u);
                    s_ent[slot] = (__float_as_uint(w) & 0xFFFFFC00u) | (unsigned)s;
                }
            }
        }
    }
    __syncthreads();   // s_ax/s_ay dead from here; s_img4 free for staging

    // ---- gather phase ----
    const int l  = tid & 63;            // lane
    const int wv = tid >> 6;            // wave 0..3: stages rows 7*wv..7*wv+6
    const size_t chan_off = (size_t)(l & 7) * HW_;
    int colg[4];
    #pragma unroll
    for (int cb = 0; cb < 4; ++cb) {
        int cx = T0x - R_ + cb * 8 + (l >> 3);
        colg[cb] = min(max(cx, 0), W_ - 1);      // clamp: safe addr, cells unused
    }
    const int oy = tid >> 4, ox = tid & (TS - 1);
    float* outp = out + (size_t)b * C_ * HW_ + (size_t)(T0y + oy) * W_ + (T0x + ox);

    for (int c0 = 0; c0 < C_; c0 += CCH) {
        // stage window [28 rows][32 cols][8 ch] via global_load_lds:
        // lds float index = (row*32 + cb*8 + (l>>3))*8 + (l&7) = row*256 + cb*64 + l
        const float* imgc = image + ((size_t)b * C_ + c0) * HW_ + chan_off;
        #pragma unroll
        for (int r7 = 0; r7 < 7; ++r7) {
            int row = wv * 7 + r7;
            int sy  = T0y - R_ + row;
            sy = min(max(sy, 0), H_ - 1);
            const float* rowp = imgc + (size_t)sy * W_;
            float* ldst = (float*)s_img4 + row * 256;
            #pragma unroll
            for (int cb = 0; cb < 4; ++cb) {
                __builtin_amdgcn_global_load_lds(
                    (GAS*)(rowp + colg[cb]),
                    (LAS*)(ldst + cb * 64), 4, 0, 0);
            }
        }
        __syncthreads();   // drains vmcnt before barrier -> staging visible

        float acc[CCH];
        #pragma unroll
        for (int c = 0; c < CCH; ++c) acc[c] = 0.0f;

        for (unsigned e = estart; e < eend; ++e) {
            unsigned pe = s_ent[e];
            float w = __uint_as_float(pe & 0xFFFFFC00u);
            unsigned si2 = (pe & 1023u) * 2;
            float4 i0 = s_img4[si2];
            float4 i1 = s_img4[si2 + 1];
            acc[0] = fmaf(i0.x, w, acc[0]);
            acc[1] = fmaf(i0.y, w, acc[1]);
            acc[2] = fmaf(i0.z, w, acc[2]);
            acc[3] = fmaf(i0.w, w, acc[3]);
            acc[4] = fmaf(i1.x, w, acc[4]);
            acc[5] = fmaf(i1.y, w, acc[5]);
            acc[6] = fmaf(i1.z, w, acc[6]);
            acc[7] = fmaf(i1.w, w, acc[7]);
        }

        #pragma unroll
        for (int c = 0; c < CCH; ++c)
            outp[(size_t)(c0 + c) * HW_] = acc[c];   // coalesced stores

        __syncthreads();   // s_img4 reused next chunk
    }
}

// Wild sources (|flow| >= R_): exact scatter with global atomics, AFTER gather.
__global__ __launch_bounds__(256) void softsplat_wild(
    const float* __restrict__ image,
    const float* __restrict__ flow,
    float* __restrict__ out)
{
    int p  = blockIdx.x * 256 + threadIdx.x;
    int b  = p >> 18;
    int yx = p & (HW_ - 1);
    int y  = yx >> 9;
    int x  = yx & (W_ - 1);

    size_t fo = (size_t)b * 2 * HW_ + yx;
    float fxr = flow[fo];
    float fyr = flow[fo + HW_];
    bool tame = (fxr >= -(float)R_) && (fxr < (float)R_) &&
                (fyr >= -(float)R_) && (fyr < (float)R_);
    if (tame) return;

    float fx = fxr + (float)x;
    float fy = fyr + (float)y;
    float x0f = floorf(fx), y0f = floorf(fy);
    int x0 = (int)x0f, y0 = (int)y0f;
    float wx1 = fx - x0f, wx0 = 1.0f - wx1;
    float wy1 = fy - y0f, wy0 = 1.0f - wy1;

    int   toff[4];
    float tw[4];
    int   nt = 0;
    int x1 = x0 + 1, y1 = y0 + 1;
    if (((unsigned)y0 < H_) & ((unsigned)x0 < W_)) { toff[nt] = y0 * W_ + x0; tw[nt] = wx0 * wy0; nt++; }
    if (((unsigned)y0 < H_) & ((unsigned)x1 < W_)) { toff[nt] = y0 * W_ + x1; tw[nt] = wx1 * wy0; nt++; }
    if (((unsigned)y1 < H_) & ((unsigned)x0 < W_)) { toff[nt] = y1 * W_ + x0; tw[nt] = wx0 * wy1; nt++; }
    if (((unsigned)y1 < H_) & ((unsigned)x1 < W_)) { toff[nt] = y1 * W_ + x1; tw[nt] = wx1 * wy1; nt++; }

    const float* img_b = image + (size_t)b * C_ * HW_ + yx;
    float*       out_b = out   + (size_t)b * C_ * HW_;
    for (int c = 0; c < C_; ++c) {
        float val = img_b[(size_t)c * HW_];
        float* oc = out_b + (size_t)c * HW_;
        #pragma unroll 4
        for (int t = 0; t < 4; ++t)
            if (t < nt) atomicAdd(oc + toff[t], val * tw[t]);
    }
}

extern "C" void kernel_launch(void* const* d_in, const int* in_sizes, int n_in,
                              void* d_out, int out_size, void* d_ws, size_t ws_size,
                              hipStream_t stream) {
    const float* image = (const float*)d_in[0];
    const float* flow  = (const float*)d_in[1];
    float* out = (float*)d_out;

    // No memset: gather writes every output element exactly once, wild adds after.
    softsplat_gather<<<4096, NTH, 0, stream>>>(image, flow, out);

    int pixels = B_ * HW_;
    softsplat_wild<<<pixels / 256, 256, 0, stream>>>(image, flow, out);
}